// Round 5
// baseline (194.614 us; speedup 1.0000x reference)
//
#include <hip/hip_runtime.h>
#include <math.h>

typedef float f32x2 __attribute__((ext_vector_type(2)));
typedef float f32x4 __attribute__((ext_vector_type(4)));

// Problem constants (setup_inputs fixed: 1x3x2048x2048 fp32)
#define HH    2048
#define WW    2048
#define NCH   3
#define NOUT  2038          // 2048 - 10 (VALID 11-tap twice)
#define OWID  64            // strip width
#define OH    128           // strip height (R10: OH=64 regressed — keep 128)
#define CROWS 16            // chunk rows (R12: CROWS=8 regressed — keep 16)
#define BUF   28            // circular ring slots (26 live max, mod-28)
#define ROWF  332           // floats per ring row: A 128 | B 128 | C 64 | pad 12
                            // (1328 B/row: 16B-aligned; 332 dw % 32 = 12 write stagger)
#define NTX   32            // 2048/64
#define NTY   16            // 2048/128
#define NBLOCKS (NTX*NTY*NCH)   // 1536
#define NOUT_TOTAL 12460332.0f  // 3 * 2038 * 2038

// SSIM per-pixel term. Scalar args, compile-time indices at call sites only
// (runtime pointer-select of register arrays caused scratch demotion in R2).
// rcpf: denominators >= 9e-4, rel err ~1e-6 vs 2e-2 threshold.
__device__ __forceinline__ float ssim_term(float mu1, float mu2,
                                           float b11, float b22, float b12) {
    const float c1v = 1e-4f, c2v = 9e-4f;
    float mu1sq = mu1 * mu1;
    float mu2sq = mu2 * mu2;
    float mu12  = mu1 * mu2;
    float s11 = b11 - mu1sq;
    float s22 = b22 - mu2sq;
    float s12 = b12 - mu12;
    float csn = 2.f * s12 + c2v;
    float csd = s11 + s22 + c2v;
    float ln  = 2.f * mu12 + c1v;
    float ld  = mu1sq + mu2sq + c1v;
    return (csn * ln) * __builtin_amdgcn_rcpf(csd * ld);
}

// R13 = exact R9 schedule (direct-global h-blur, 28-slot ring, PF-before-C
// prefetch, 2 barriers/chunk, scalar xy channel) with VALU-count reductions
// only. Empirical law R9-R12: dur ~= VALU_work / 0.53 — structure changes
// (OH=64 R10, pk-xy R11, CROWS=8 R12) all regressed by exactly their added
// work; occupancy counter never responded. So: cut instructions, keep
// structure. (a) fused ring row [A|B|C] -> stage C's 3 reads share one base
// (ds_read2-combinable A/B, const offsets), BLUR's 5 stores share one base;
// saves ~250 VALU/thread (~6%). (b) hoisted uniform clamp-path flags
// (xint/yint) and colok. LDS unchanged 37.2 KB -> 4 blocks/CU.
// fp32 throughout (R5 fp16 regressed). __launch_bounds__(256,2): (256,4)
// caps VGPR at 64 -> catastrophic spill (R3). VGPR must stay <=128.
__global__ __launch_bounds__(256, 2)
void ssim_main(const float* __restrict__ x, const float* __restrict__ y,
               float* __restrict__ partials) {
    __shared__ float hb[BUF][ROWF];      // fused ring: 37.2 KB
    __shared__ float wsum[4];            // -> 4 blocks/CU

    const int tid = threadIdx.x;
    const int gx0 = blockIdx.x * OWID;
    const int gy0 = blockIdx.y * OH;
    const float* xb = x + (size_t)blockIdx.z * HH * WW;
    const float* yb = y + (size_t)blockIdx.z * HH * WW;

    // Uniform edge-path flags (runtime-uniform per block; 15/16 of blocks
    // take the clampless fast path).
    const bool xint = (gx0 + 80 <= WW);   // loads reach gx0+73 max
    const bool yint = (gy0 + 138 <= HH);  // PF rows reach gy0+137 max

    // Gaussian weights (11 taps, sigma 1.5), normalized — matches jnp f32
    float w[11];
    {
        float s = 0.f;
        #pragma unroll
        for (int i = 0; i < 11; ++i) {
            float d = (float)(i - 5);
            w[i] = expf(-d * d / 4.5f);
            s += w[i];
        }
        float inv = 1.f / s;
        #pragma unroll
        for (int i = 0; i < 11; ++i) w[i] *= inv;
    }

    // h-blur geometry: thread (lr, c0) produces ring row lr, pair cols
    // [c0, c0+4) from input cols [c0, c0+14). 16 rows x 16 col-groups.
    const int lr  = tid >> 4;            // 0..15
    const int c0  = (tid & 15) * 4;      // 0..60
    const int gxc = gx0 + c0;

    // Prefetch registers: 14 input cols x 2 images = 28 VGPRs, live across C.
    f32x4 px[3], py[3];
    f32x2 px3, py3;

    // Issue the global loads for h-rows [base, base+16) (this thread's slice).
    auto PF = [&](int base) {
        int gy = gy0 + base + lr;
        if (!yint) gy = gy > HH - 1 ? HH - 1 : gy;
        const float* xr = xb + (size_t)gy * WW;
        const float* yr = yb + (size_t)gy * WW;
        if (xint) {
            #pragma unroll
            for (int a = 0; a < 3; ++a) {
                px[a] = *(const f32x4*)(xr + gxc + 4 * a);
                py[a] = *(const f32x4*)(yr + gxc + 4 * a);
            }
            px3 = *(const f32x2*)(xr + gxc + 12);
            py3 = *(const f32x2*)(yr + gxc + 12);
        } else {  // right-edge clamp; feeds only guarded outputs
            #pragma unroll
            for (int a = 0; a < 3; ++a) {
                int g = gxc + 4 * a;
                int g0 = g     < WW ? g     : WW - 1;
                int g1 = g + 1 < WW ? g + 1 : WW - 1;
                int g2 = g + 2 < WW ? g + 2 : WW - 1;
                int g3 = g + 3 < WW ? g + 3 : WW - 1;
                px[a] = (f32x4){xr[g0], xr[g1], xr[g2], xr[g3]};
                py[a] = (f32x4){yr[g0], yr[g1], yr[g2], yr[g3]};
            }
            int g = gxc + 12;
            int g0 = g     < WW ? g     : WW - 1;
            int g1 = g + 1 < WW ? g + 1 : WW - 1;
            px3 = (f32x2){xr[g0], xr[g1]};
            py3 = (f32x2){yr[g0], yr[g1]};
        }
    };

    // h-blur the prefetched row into ring slot (base+lr)%28.
    // tailMask: prologue partial chunk (rows [16,26)) — threads lr>=10
    // compute but must not store (their slot would alias live rows).
    auto BLUR = [&](int base, bool tailMask) {
        int slot = (base + lr) % BUF;
        f32x2 p[14];
        #pragma unroll
        for (int a = 0; a < 3; ++a)
            #pragma unroll
            for (int i = 0; i < 4; ++i)
                p[4 * a + i] = (f32x2){px[a][i], py[a][i]};
        p[12] = (f32x2){px3.x, py3.x};
        p[13] = (f32x2){px3.y, py3.y};
        f32x2 q[14]; float pr[14];
        #pragma unroll
        for (int t = 0; t < 14; ++t) {
            q[t]  = p[t] * p[t];             // v_pk_mul_f32
            pr[t] = p[t].x * p[t].y;
        }
        f32x2 hA[4] = {}, hB[4] = {};
        float hC[4] = {};
        #pragma unroll
        for (int k = 0; k < 11; ++k) {
            f32x2 wk2 = (f32x2){w[k], w[k]};
            #pragma unroll
            for (int j = 0; j < 4; ++j) {
                hA[j] = __builtin_elementwise_fma(wk2, p[j + k], hA[j]);
                hB[j] = __builtin_elementwise_fma(wk2, q[j + k], hB[j]);
                hC[j] = fmaf(w[k], pr[j + k], hC[j]);
            }
        }
        if (!tailMask || lr < 10) {
            // One base pointer, 5 stores at constant offsets (16B-aligned:
            // 2*c0 mult of 8 floats, row base 1328B mult of 16).
            float* row = &hb[slot][0];
            *(f32x4*)(row + 2 * c0)           = (f32x4){hA[0].x, hA[0].y, hA[1].x, hA[1].y};
            *(f32x4*)(row + 2 * c0 + 4)       = (f32x4){hA[2].x, hA[2].y, hA[3].x, hA[3].y};
            *(f32x4*)(row + 128 + 2 * c0)     = (f32x4){hB[0].x, hB[0].y, hB[1].x, hB[1].y};
            *(f32x4*)(row + 128 + 2 * c0 + 4) = (f32x4){hB[2].x, hB[2].y, hB[3].x, hB[3].y};
            *(float4*)(row + 256 + c0)        = make_float4(hC[0], hC[1], hC[2], hC[3]);
        }
    };

    float partial = 0.f;

    // Prologue: h-rows [0,26) into the ring (26 live = max).
    PF(0);  BLUR(0, false);
    PF(16); BLUR(16, true);
    __syncthreads();

    const int col  = tid & 63;
    const int wid  = tid >> 6;           // wave id -> slot math is wave-uniform
    const int ocol = gx0 + col;
    const bool colok = ocol < NOUT;

    // Main loop: 8 chunks of 16 output rows. Invariant before C(m): ring holds
    // h-rows [16m, 16m+26). C(m) consumes the window; after the barrier, BLUR
    // overwrites the 16 dead slots (rows 16m+26..16m+42 land on rows-28 slots).
    for (int m = 0; m < 8; ++m) {
        if (m < 7) PF(16 * m + 26);      // in flight during stage C
        {   // Stage C: v-blur, 1 col x 4 rows per thread, sliding window:
            // read ring row once (A/B/C share one base; A+B ds_read2-pairable),
            // feed its <=4 output accumulators. FP order per output is k
            // ascending — identical to the batched version.
            const int r0 = 16 * m + wid * 4;
            int s = r0 % BUF;
            f32x2 aA[4] = {}, aB[4] = {};
            float aC[4] = {};
            #pragma unroll
            for (int j = 0; j < 14; ++j) {
                const float* row = &hb[s][0];
                f32x2 va = *(const f32x2*)(row + 2 * col);
                f32x2 vb = *(const f32x2*)(row + 128 + 2 * col);
                float vc = row[256 + col];
                #pragma unroll
                for (int i = 0; i < 4; ++i) {
                    const int k = j - i;
                    if (k >= 0 && k < 11) {
                        f32x2 wk2 = (f32x2){w[k], w[k]};
                        aA[i] = __builtin_elementwise_fma(wk2, va, aA[i]);
                        aB[i] = __builtin_elementwise_fma(wk2, vb, aB[i]);
                        aC[i] = fmaf(w[k], vc, aC[i]);
                    }
                }
                s = (s == BUF - 1) ? 0 : s + 1;
            }
            #pragma unroll
            for (int i = 0; i < 4; ++i) {
                int orow = gy0 + r0 + i;
                if (colok && orow < NOUT)
                    partial += ssim_term(aA[i].x, aA[i].y, aB[i].x, aB[i].y, aC[i]);
            }
        }
        __syncthreads();                 // C reads done before BLUR overwrites
        if (m < 7) {
            BLUR(16 * m + 26, false);
            __syncthreads();             // ring writes visible for next C
        }
    }

    // Reduction: wave shuffle -> block -> one plain store per block.
    #pragma unroll
    for (int off = 32; off > 0; off >>= 1)
        partial += __shfl_down(partial, off, 64);
    if ((tid & 63) == 0) wsum[tid >> 6] = partial;
    __syncthreads();
    if (tid == 0) {
        int bid = (blockIdx.z * gridDim.y + blockIdx.y) * gridDim.x + blockIdx.x;
        partials[bid] = wsum[0] + wsum[1] + wsum[2] + wsum[3];
    }
}

__global__ __launch_bounds__(256)
void ssim_finalize(const float* __restrict__ partials, float* __restrict__ out) {
    __shared__ float ws[4];
    float s = 0.f;
    // NBLOCKS = 1536 = 384 float4s
    for (int i = threadIdx.x; i < NBLOCKS / 4; i += 256) {
        float4 v = ((const float4*)partials)[i];
        s += (v.x + v.y) + (v.z + v.w);
    }
    #pragma unroll
    for (int off = 32; off > 0; off >>= 1)
        s += __shfl_down(s, off, 64);
    if ((threadIdx.x & 63) == 0) ws[threadIdx.x >> 6] = s;
    __syncthreads();
    if (threadIdx.x == 0)
        out[0] = 1.f - (ws[0] + ws[1] + ws[2] + ws[3]) / NOUT_TOTAL;
}

extern "C" void kernel_launch(void* const* d_in, const int* in_sizes, int n_in,
                              void* d_out, int out_size, void* d_ws, size_t ws_size,
                              hipStream_t stream) {
    const float* x = (const float*)d_in[0];
    const float* y = (const float*)d_in[1];
    float* out = (float*)d_out;
    float* partials = (float*)d_ws;   // NBLOCKS floats = 6 KB of scratch

    dim3 grid(NTX, NTY, NCH);
    ssim_main<<<grid, dim3(256), 0, stream>>>(x, y, partials);
    ssim_finalize<<<1, 256, 0, stream>>>(partials, out);
}

// Round 6
// 180.181 us; speedup vs baseline: 1.0801x; 1.0801x over previous
//
#include <hip/hip_runtime.h>
#include <math.h>

typedef float f32x2 __attribute__((ext_vector_type(2)));
typedef float f32x4 __attribute__((ext_vector_type(4)));

// Problem constants (setup_inputs fixed: 1x3x2048x2048 fp32)
#define HH    2048
#define WW    2048
#define NCH   3
#define NOUT  2038          // 2048 - 10 (VALID 11-tap twice)
#define OWID  64            // strip width
#define OH    128           // strip height (R10: OH=64 regressed — keep 128)
#define CROWS 16            // chunk rows (R12: CROWS=8 regressed — keep 16)
#define BUF   28            // circular h-blur buffer slots (26 live max, mod-28)
#define HAW   66            // hbA/hbB stride in pairs: 528B rows (R7-proven; R13's
                            // fused 1328B row regressed — keep separate arrays)
#define HCW   68            // hbC stride in floats: 272B rows
#define NTX   32            // 2048/64
#define NTY   16            // 2048/128
#define NBLOCKS (NTX*NTY*NCH)   // 1536
#define NOUT_TOTAL 12460332.0f  // 3 * 2038 * 2038

// SSIM per-pixel term. Scalar args, compile-time indices at call sites only
// (runtime pointer-select of register arrays caused scratch demotion in R2).
// rcpf: denominators >= 9e-4, rel err ~1e-6 vs 2e-2 threshold.
__device__ __forceinline__ float ssim_term(float mu1, float mu2,
                                           float b11, float b22, float b12) {
    const float c1v = 1e-4f, c2v = 9e-4f;
    float mu1sq = mu1 * mu1;
    float mu2sq = mu2 * mu2;
    float mu12  = mu1 * mu2;
    float s11 = b11 - mu1sq;
    float s22 = b22 - mu2sq;
    float s12 = b12 - mu12;
    float csn = 2.f * s12 + c2v;
    float csd = s11 + s22 + c2v;
    float ln  = 2.f * mu12 + c1v;
    float ld  = mu1sq + mu2sq + c1v;
    return (csn * ln) * __builtin_amdgcn_rcpf(csd * ld);
}

// R14 = byte-identical R9 layout/schedule (the proven 74us local optimum:
// direct-global h-blur, 28-slot ring, separate hbA/hbB/hbC 528B/272B rows,
// 2 barriers/chunk, scalar xy channel) + ONE change: the PF prefetch is now
// 2 chunks deep via double-buffered register sets A/B (issue L(m+1) before
// C(m), consume L(m) after C(m)). R9's stall: C is ~700cy but HBM latency is
// ~900cy, so BLUR waited on vmcnt every chunk (VALUBusy 55%). Cover is now
// ~2 chunks. +28 VGPR is FREE: LDS caps residency at 4 blocks/CU = 4
// waves/SIMD, and VGPR<=128 allows that (m69 boundary). Loop unrolled x2 so
// A/B selection is compile-time (runtime-indexed reg arrays -> scratch, R2).
// Failed-experiment ledger: OH=64 (R10), pk-xy (R11), CROWS=8 (R12), fused
// row (R13) — all regressed; VALU work is constant ~41us, only stalls move.
// fp32 throughout (R5 fp16 regressed). __launch_bounds__(256,2): (256,4)
// caps VGPR at 64 -> catastrophic spill (R3).
__global__ __launch_bounds__(256, 2)
void ssim_main(const float* __restrict__ x, const float* __restrict__ y,
               float* __restrict__ partials) {
    __shared__ f32x2 hbA[BUF][HAW];      // (mu1,mu2) h-blur ring: 14.4 KB
    __shared__ f32x2 hbB[BUF][HAW];      // (xx,yy)  h-blur ring: 14.4 KB
    __shared__ float hbC[BUF][HCW];      // xy       h-blur ring:  7.4 KB
    __shared__ float wsum[4];            // total 37.2 KB -> 4 blocks/CU

    const int tid = threadIdx.x;
    const int gx0 = blockIdx.x * OWID;
    const int gy0 = blockIdx.y * OH;
    const float* xb = x + (size_t)blockIdx.z * HH * WW;
    const float* yb = y + (size_t)blockIdx.z * HH * WW;

    // Gaussian weights (11 taps, sigma 1.5), normalized — matches jnp f32
    float w[11];
    {
        float s = 0.f;
        #pragma unroll
        for (int i = 0; i < 11; ++i) {
            float d = (float)(i - 5);
            w[i] = expf(-d * d / 4.5f);
            s += w[i];
        }
        float inv = 1.f / s;
        #pragma unroll
        for (int i = 0; i < 11; ++i) w[i] *= inv;
    }

    // h-blur geometry: thread (lr, c0) produces ring row lr, pair cols
    // [c0, c0+4) from input cols [c0, c0+14).
    const int lr  = tid >> 4;            // 0..15
    const int c0  = (tid & 15) * 4;      // 0..60
    const int gxc = gx0 + c0;

    // Two prefetch register sets (2-deep pipeline): 2 x 28 VGPRs.
    f32x4 pxA[3], pyA[3]; f32x2 px3A, py3A;
    f32x4 pxB[3], pyB[3]; f32x2 px3B, py3B;

// Issue the global loads for h-rows [base, base+16) into set S.
#define PF_IMPL(px_, py_, px3_, py3_, base_) do {                              \
    int gy = gy0 + (base_) + lr; if (gy > HH - 1) gy = HH - 1;                 \
    const float* xr = xb + (size_t)gy * WW;                                    \
    const float* yr = yb + (size_t)gy * WW;                                    \
    _Pragma("unroll")                                                          \
    for (int a = 0; a < 3; ++a) {                                              \
        int g = gxc + 4 * a;                                                   \
        if (g + 4 <= WW) {                                                     \
            px_[a] = *(const f32x4*)(xr + g);                                  \
            py_[a] = *(const f32x4*)(yr + g);                                  \
        } else {  /* right-edge clamp; feeds only guarded outputs */           \
            int g0 = g     < WW ? g     : WW - 1;                              \
            int g1 = g + 1 < WW ? g + 1 : WW - 1;                              \
            int g2 = g + 2 < WW ? g + 2 : WW - 1;                              \
            int g3 = g + 3 < WW ? g + 3 : WW - 1;                              \
            px_[a] = (f32x4){xr[g0], xr[g1], xr[g2], xr[g3]};                  \
            py_[a] = (f32x4){yr[g0], yr[g1], yr[g2], yr[g3]};                  \
        }                                                                      \
    }                                                                          \
    {                                                                          \
        int g = gxc + 12;                                                      \
        if (g + 2 <= WW) {                                                     \
            px3_ = *(const f32x2*)(xr + g);                                    \
            py3_ = *(const f32x2*)(yr + g);                                    \
        } else {                                                               \
            int g0 = g     < WW ? g     : WW - 1;                              \
            int g1 = g + 1 < WW ? g + 1 : WW - 1;                              \
            px3_ = (f32x2){xr[g0], xr[g1]};                                    \
            py3_ = (f32x2){yr[g0], yr[g1]};                                    \
        }                                                                      \
    }                                                                          \
} while (0)
#define PF_A(base_) PF_IMPL(pxA, pyA, px3A, py3A, base_)
#define PF_B(base_) PF_IMPL(pxB, pyB, px3B, py3B, base_)

// h-blur set S into ring slot (base+lr)%28. tailMask: prologue partial chunk
// (rows [16,26)) — threads lr>=10 compute but must not store.
#define BLUR_IMPL(px_, py_, px3_, py3_, base_, tailMask_) do {                 \
    int slot = ((base_) + lr) % BUF;                                           \
    f32x2 p[14];                                                               \
    _Pragma("unroll")                                                          \
    for (int a = 0; a < 3; ++a) {                                              \
        _Pragma("unroll")                                                      \
        for (int i = 0; i < 4; ++i)                                            \
            p[4 * a + i] = (f32x2){px_[a][i], py_[a][i]};                      \
    }                                                                          \
    p[12] = (f32x2){px3_.x, py3_.x};                                           \
    p[13] = (f32x2){px3_.y, py3_.y};                                           \
    f32x2 q[14]; float pr[14];                                                 \
    _Pragma("unroll")                                                          \
    for (int t = 0; t < 14; ++t) {                                             \
        q[t]  = p[t] * p[t];             /* v_pk_mul_f32 */                    \
        pr[t] = p[t].x * p[t].y;                                               \
    }                                                                          \
    f32x2 hA[4] = {}, hB[4] = {};                                              \
    float hC[4] = {};                                                          \
    _Pragma("unroll")                                                          \
    for (int k = 0; k < 11; ++k) {                                             \
        f32x2 wk2 = (f32x2){w[k], w[k]};                                       \
        _Pragma("unroll")                                                      \
        for (int j = 0; j < 4; ++j) {                                          \
            hA[j] = __builtin_elementwise_fma(wk2, p[j + k], hA[j]);           \
            hB[j] = __builtin_elementwise_fma(wk2, q[j + k], hB[j]);           \
            hC[j] = fmaf(w[k], pr[j + k], hC[j]);                              \
        }                                                                      \
    }                                                                          \
    if (!(tailMask_) || lr < 10) {                                             \
        /* b128 stores (rows 528B/272B, c0 mult of 4 -> 16B-aligned) */        \
        *(f32x4*)&hbA[slot][c0]     = (f32x4){hA[0].x, hA[0].y, hA[1].x, hA[1].y}; \
        *(f32x4*)&hbA[slot][c0 + 2] = (f32x4){hA[2].x, hA[2].y, hA[3].x, hA[3].y}; \
        *(f32x4*)&hbB[slot][c0]     = (f32x4){hB[0].x, hB[0].y, hB[1].x, hB[1].y}; \
        *(f32x4*)&hbB[slot][c0 + 2] = (f32x4){hB[2].x, hB[2].y, hB[3].x, hB[3].y}; \
        *(float4*)&hbC[slot][c0]    = make_float4(hC[0], hC[1], hC[2], hC[3]); \
    }                                                                          \
} while (0)
#define BLUR_A(base_, t_) BLUR_IMPL(pxA, pyA, px3A, py3A, base_, t_)
#define BLUR_B(base_, t_) BLUR_IMPL(pxB, pyB, px3B, py3B, base_, t_)

    float partial = 0.f;

    const int col  = tid & 63;
    const int wid  = tid >> 6;           // wave id -> slot math is wave-uniform
    const int ocol = gx0 + col;

    // Stage C: v-blur, 1 col x 4 rows per thread, sliding window: read ring
    // row once, feed its <=4 output accumulators. FP order per output is k
    // ascending — identical to R9.
    auto CSTAGE = [&](int m) {
        const int r0 = 16 * m + wid * 4;
        int s = r0 % BUF;
        f32x2 aA[4] = {}, aB[4] = {};
        float aC[4] = {};
        #pragma unroll
        for (int j = 0; j < 14; ++j) {
            f32x2 va = hbA[s][col];
            f32x2 vb = hbB[s][col];
            float vc = hbC[s][col];
            #pragma unroll
            for (int i = 0; i < 4; ++i) {
                const int k = j - i;
                if (k >= 0 && k < 11) {
                    f32x2 wk2 = (f32x2){w[k], w[k]};
                    aA[i] = __builtin_elementwise_fma(wk2, va, aA[i]);
                    aB[i] = __builtin_elementwise_fma(wk2, vb, aB[i]);
                    aC[i] = fmaf(w[k], vc, aC[i]);
                }
            }
            s = (s == BUF - 1) ? 0 : s + 1;
        }
        #pragma unroll
        for (int i = 0; i < 4; ++i) {
            int orow = gy0 + r0 + i;
            if (orow < NOUT && ocol < NOUT)
                partial += ssim_term(aA[i].x, aA[i].y, aB[i].x, aB[i].y, aC[i]);
        }
    };

    // Prologue: h-rows [0,26) into the ring (26 live = max), then L(0)
    // (rows 26..41) issued into set A, in flight across the barrier.
    PF_A(0);  BLUR_A(0, false);
    PF_A(16); BLUR_A(16, true);
    PF_A(26);
    __syncthreads();

    // Main loop, unrolled x2 for compile-time A/B selection. Invariant before
    // C(m): ring holds h-rows [16m, 16m+26); L(m) = rows 16m+26 is in flight
    // (issued one chunk earlier). L(m+1) is issued before C(m) -> its latency
    // is covered by C(m)+BLUR(m)+C(m+1).
    for (int mm = 0; mm < 4; ++mm) {
        {   // m = 2*mm (even): consume A, issue into B
            const int m = 2 * mm;
            if (mm < 3) PF_B(16 * m + 42);        // L(m+1), m=0,2,4
            CSTAGE(m);
            __syncthreads();                      // C reads done before BLUR
            BLUR_A(16 * m + 26, false);           // m=0,2,4,6 all < 7
            __syncthreads();                      // ring writes visible
        }
        {   // m = 2*mm+1 (odd): consume B, issue into A
            const int m = 2 * mm + 1;
            if (mm < 3) PF_A(16 * m + 42);        // L(m+1), m=1,3,5
            CSTAGE(m);
            __syncthreads();
            if (mm < 3) {                         // no BLUR at m=7
                BLUR_B(16 * m + 26, false);
                __syncthreads();
            }
        }
    }

    // Reduction: wave shuffle -> block -> one plain store per block.
    #pragma unroll
    for (int off = 32; off > 0; off >>= 1)
        partial += __shfl_down(partial, off, 64);
    if ((tid & 63) == 0) wsum[tid >> 6] = partial;
    __syncthreads();
    if (tid == 0) {
        int bid = (blockIdx.z * gridDim.y + blockIdx.y) * gridDim.x + blockIdx.x;
        partials[bid] = wsum[0] + wsum[1] + wsum[2] + wsum[3];
    }
}

__global__ __launch_bounds__(256)
void ssim_finalize(const float* __restrict__ partials, float* __restrict__ out) {
    __shared__ float ws[4];
    float s = 0.f;
    // NBLOCKS = 1536 = 384 float4s
    for (int i = threadIdx.x; i < NBLOCKS / 4; i += 256) {
        float4 v = ((const float4*)partials)[i];
        s += (v.x + v.y) + (v.z + v.w);
    }
    #pragma unroll
    for (int off = 32; off > 0; off >>= 1)
        s += __shfl_down(s, off, 64);
    if ((threadIdx.x & 63) == 0) ws[threadIdx.x >> 6] = s;
    __syncthreads();
    if (threadIdx.x == 0)
        out[0] = 1.f - (ws[0] + ws[1] + ws[2] + ws[3]) / NOUT_TOTAL;
}

extern "C" void kernel_launch(void* const* d_in, const int* in_sizes, int n_in,
                              void* d_out, int out_size, void* d_ws, size_t ws_size,
                              hipStream_t stream) {
    const float* x = (const float*)d_in[0];
    const float* y = (const float*)d_in[1];
    float* out = (float*)d_out;
    float* partials = (float*)d_ws;   // NBLOCKS floats = 6 KB of scratch

    dim3 grid(NTX, NTY, NCH);
    ssim_main<<<grid, dim3(256), 0, stream>>>(x, y, partials);
    ssim_finalize<<<1, 256, 0, stream>>>(partials, out);
}

// Round 7
// 170.957 us; speedup vs baseline: 1.1384x; 1.0540x over previous
//
#include <hip/hip_runtime.h>
#include <math.h>

typedef float f32x2 __attribute__((ext_vector_type(2)));

// Problem constants (setup_inputs fixed: 1x3x2048x2048 fp32)
#define HH    2048
#define WW    2048
#define NCH   3
#define NOUT  2038          // 2048 - 10 (VALID 11-tap twice)
#define SH    45            // output rows per segment: 55 input rows = 5x11 exact
#define NSEG  46            // ceil(2038/45)
#define NBX   8             // 2048/256 column blocks
#define NBLOCKS (NBX*NSEG*NCH)  // 1104
#define NOUT_TOTAL 12460332.0f  // 3 * 2038 * 2038

// SSIM per-pixel term. rcpf: denominators >= 9e-4, rel err ~1e-6 vs 2e-2
// threshold.
__device__ __forceinline__ float ssim_term(float mu1, float mu2,
                                           float b11, float b22, float b12) {
    const float c1v = 1e-4f, c2v = 9e-4f;
    float mu1sq = mu1 * mu1;
    float mu2sq = mu2 * mu2;
    float mu12  = mu1 * mu2;
    float s11 = b11 - mu1sq;
    float s22 = b22 - mu2sq;
    float s12 = b12 - mu12;
    float csn = 2.f * s12 + c2v;
    float csd = s11 + s22 + c2v;
    float ln  = 2.f * mu12 + c1v;
    float ld  = mu1sq + mu2sq + c1v;
    return (csn * ln) * __builtin_amdgcn_rcpf(csd * ld);
}

// R15: BARRIER-FREE column-streaming rewrite. Ledger R10-R14: five structural
// perturbations of the block-ring design all regressed; VALUBusy*dur was
// invariant ~40us — the producer/consumer barrier chain (17 all-wave drains
// per block) was the stall, not the layout. New structure: thread = 1 output
// column, slides down a 45-output-row segment. Per row: wave stages its 75-col
// row span into WAVE-PRIVATE LDS (2 coalesced loads/img, no __syncthreads —
// wave-internal visibility via lgkmcnt only), lanes ds_read_b64 their 11
// (x,y)-pair taps (pair-aligned -> zero packing movs), h-blur 55 VALU,
// scatter-accumulate into 11 register output-accumulators (k ascending per
// output — FP order identical to R9; k=0 is a mul overwrite, no zeroing).
// One output emitted per row. Loads for row+1 issued before row's compute.
// No barriers, no ring re-reads, no 3.5x-halo BLUR -> VALU floor ~21us.
// VGPR must stay <=128 (m69 wave-slot boundary); __launch_bounds__(256,2)
// ((256,4) historically forced a 64-VGPR cap -> spills, R3).
__global__ __launch_bounds__(256, 2)
void ssim_main(const float* __restrict__ x, const float* __restrict__ y,
               float* __restrict__ partials) {
    __shared__ f32x2 stage[2][4][80];    // [rowparity][wave][75 used]: 5.1 KB
    __shared__ float wsum[4];

    const int tid  = threadIdx.x;
    const int lane = tid & 63;
    const int wid  = tid >> 6;
    const int col  = blockIdx.x * 256 + tid;     // 0..2047
    const int r0   = blockIdx.y * SH;
    const float* xb = x + (size_t)blockIdx.z * HH * WW;
    const float* yb = y + (size_t)blockIdx.z * HH * WW;

    // Gaussian weights (11 taps, sigma 1.5), normalized — matches jnp f32.
    // Stored ONLY as (w,w) pairs; scalar uses read the low component (saves
    // 11 VGPR vs separate scalar array).
    f32x2 w2[11];
    {
        float wtmp[11];
        float s = 0.f;
        #pragma unroll
        for (int i = 0; i < 11; ++i) {
            float d = (float)(i - 5);
            wtmp[i] = expf(-d * d / 4.5f);
            s += wtmp[i];
        }
        float inv = 1.f / s;
        #pragma unroll
        for (int i = 0; i < 11; ++i) w2[i] = (f32x2){wtmp[i] * inv, wtmp[i] * inv};
    }

    // Second stage-load column (tail lanes fill slots 64..79); clamp keeps all
    // loads in-bounds. Clamped values only ever feed masked outputs.
    const int  cB    = (col + 64 < HH) ? col + 64 : HH - 1;
    const bool colok = col < NOUT;
    const bool tail  = lane < 16;

    // 11 live output accumulators (5 channels: A=(mu1,mu2) B=(b11,b22) C=b12).
    // Slot o%11 holds output row o. k=0 scatter overwrites (mul), so init is
    // only needed to keep the first 10 phases' fma inputs defined.
    f32x2 accA[11], accB[11];
    float accC[11];
    #pragma unroll
    for (int i = 0; i < 11; ++i) {
        accA[i] = (f32x2){0.f, 0.f};
        accB[i] = (f32x2){0.f, 0.f};
        accC[i] = 0.f;
    }

    float partial = 0.f;

    // Current-row staging registers (loaded one phase ahead).
    float cx0, cy0, cx1, cy1;
    {
        const float* xr = xb + (size_t)r0 * WW;
        const float* yr = yb + (size_t)r0 * WW;
        cx0 = xr[col]; cy0 = yr[col];
        cx1 = xr[cB];  cy1 = yr[cB];
    }

// One row-phase. PH is a LITERAL (0..10) so every acc index is compile-time
// (runtime-indexed register arrays -> scratch, R2 lesson). VB is the runtime
// 11-row group base. EMIT=false only for the first 10 warm-up phases.
#define PHASE(VB, PH, EMIT) do {                                               \
    const int vrow = (VB) + (PH);                                              \
    /* prefetch next input row (clamped; wasted only on the very last phase) */\
    int nrow = r0 + vrow + 1; nrow = nrow < HH ? nrow : HH - 1;                \
    const float* xr = xb + (size_t)nrow * WW;                                  \
    const float* yr = yb + (size_t)nrow * WW;                                  \
    float nx0 = xr[col], ny0 = yr[col];                                        \
    float nx1 = xr[cB],  ny1 = yr[cB];                                         \
    /* stage current row as (x,y) pairs in this wave's private line */         \
    f32x2* sb = &stage[vrow & 1][wid][0];                                      \
    sb[lane] = (f32x2){cx0, cy0};                                              \
    if (tail) sb[64 + lane] = (f32x2){cx1, cy1};                               \
    /* 11 taps, ds_read_b64, pair-aligned -> pk-ready with zero movs */        \
    f32x2 p[11];                                                               \
    _Pragma("unroll")                                                          \
    for (int j = 0; j < 11; ++j) p[j] = sb[lane + j];                          \
    /* h-blur, k ascending (reference order) */                                \
    f32x2 hA = w2[0] * p[0];                                                   \
    f32x2 hB = w2[0] * (p[0] * p[0]);                                          \
    float hC = w2[0].x * (p[0].x * p[0].y);                                    \
    _Pragma("unroll")                                                          \
    for (int k = 1; k < 11; ++k) {                                             \
        hA = __builtin_elementwise_fma(w2[k], p[k], hA);                       \
        hB = __builtin_elementwise_fma(w2[k], p[k] * p[k], hB);                \
        hC = fmaf(w2[k].x, p[k].x * p[k].y, hC);                               \
    }                                                                          \
    /* v-blur scatter: output o=vrow-k gets tap k now; rows ascending means */ \
    /* each output accumulates k=0,1,...,10 — identical order to R9's C.    */ \
    /* k=0 overwrites (mul): slot PH was emitted+freed last phase.          */ \
    accA[(PH)] = w2[0] * hA;                                                   \
    accB[(PH)] = w2[0] * hB;                                                   \
    accC[(PH)] = w2[0].x * hC;                                                 \
    _Pragma("unroll")                                                          \
    for (int k = 1; k < 11; ++k) {                                             \
        const int sidx = ((PH) + 11 - k) % 11;                                 \
        accA[sidx] = __builtin_elementwise_fma(w2[k], hA, accA[sidx]);         \
        accB[sidx] = __builtin_elementwise_fma(w2[k], hB, accB[sidx]);         \
        accC[sidx] = fmaf(w2[k].x, hC, accC[sidx]);                            \
    }                                                                          \
    /* slot (PH+1)%11 just received its k=10 tap -> output vrow-10 complete */ \
    if (EMIT) {                                                                \
        const int e = ((PH) + 1) % 11;                                         \
        const int orow = r0 + vrow - 10;                                       \
        if (orow < NOUT && colok)                                              \
            partial += ssim_term(accA[e].x, accA[e].y,                         \
                                 accB[e].x, accB[e].y, accC[e]);               \
    }                                                                          \
    cx0 = nx0; cy0 = ny0; cx1 = nx1; cy1 = ny1;                                \
} while (0)

    // Warm-up: input rows 0..9 (no output yet), row 10 emits output row 0.
    PHASE(0, 0, false); PHASE(0, 1, false); PHASE(0, 2, false);
    PHASE(0, 3, false); PHASE(0, 4, false); PHASE(0, 5, false);
    PHASE(0, 6, false); PHASE(0, 7, false); PHASE(0, 8, false);
    PHASE(0, 9, false); PHASE(0, 10, true);

    // Main: 4 more groups of 11 rows, one output per row. Keep the group loop
    // rolled (full unroll would be ~42 KB of code, past I-cache).
    #pragma unroll 1
    for (int it = 1; it < 5; ++it) {
        const int vb = it * 11;
        PHASE(vb, 0, true);  PHASE(vb, 1, true);  PHASE(vb, 2, true);
        PHASE(vb, 3, true);  PHASE(vb, 4, true);  PHASE(vb, 5, true);
        PHASE(vb, 6, true);  PHASE(vb, 7, true);  PHASE(vb, 8, true);
        PHASE(vb, 9, true);  PHASE(vb, 10, true);
    }

    // Reduction: wave shuffle -> block -> one plain store per block.
    #pragma unroll
    for (int off = 32; off > 0; off >>= 1)
        partial += __shfl_down(partial, off, 64);
    if ((tid & 63) == 0) wsum[tid >> 6] = partial;
    __syncthreads();
    if (tid == 0) {
        int bid = (blockIdx.z * gridDim.y + blockIdx.y) * gridDim.x + blockIdx.x;
        partials[bid] = wsum[0] + wsum[1] + wsum[2] + wsum[3];
    }
}

__global__ __launch_bounds__(256)
void ssim_finalize(const float* __restrict__ partials, float* __restrict__ out) {
    __shared__ float ws[4];
    float s = 0.f;
    // NBLOCKS = 1104 = 276 float4s
    for (int i = threadIdx.x; i < NBLOCKS / 4; i += 256) {
        float4 v = ((const float4*)partials)[i];
        s += (v.x + v.y) + (v.z + v.w);
    }
    #pragma unroll
    for (int off = 32; off > 0; off >>= 1)
        s += __shfl_down(s, off, 64);
    if ((threadIdx.x & 63) == 0) ws[threadIdx.x >> 6] = s;
    __syncthreads();
    if (threadIdx.x == 0)
        out[0] = 1.f - (ws[0] + ws[1] + ws[2] + ws[3]) / NOUT_TOTAL;
}

extern "C" void kernel_launch(void* const* d_in, const int* in_sizes, int n_in,
                              void* d_out, int out_size, void* d_ws, size_t ws_size,
                              hipStream_t stream) {
    const float* x = (const float*)d_in[0];
    const float* y = (const float*)d_in[1];
    float* out = (float*)d_out;
    float* partials = (float*)d_ws;   // NBLOCKS floats = 4.4 KB of scratch

    dim3 grid(NBX, NSEG, NCH);
    ssim_main<<<grid, dim3(256), 0, stream>>>(x, y, partials);
    ssim_finalize<<<1, 256, 0, stream>>>(partials, out);
}

// Round 8
// 156.248 us; speedup vs baseline: 1.2455x; 1.0941x over previous
//
#include <hip/hip_runtime.h>
#include <math.h>

typedef float f32x2 __attribute__((ext_vector_type(2)));
typedef float f32x4 __attribute__((ext_vector_type(4)));

// Problem constants (setup_inputs fixed: 1x3x2048x2048 fp32)
#define HH    2048
#define WW    2048
#define NCH   3
#define NOUT  2038          // 2048 - 10 (VALID 11-tap twice)
#define OWID  64            // block strip width (4 waves x 16)
#define SW    16            // per-WAVE strip width
#define OH    128           // strip height (R10: OH=64 regressed)
#define CROWS 16            // chunk rows (R12: CROWS=8 regressed)
#define BUF   28            // ring slots per wave (26 live max, mod-28)
#define APW   17            // hbA/hbB slot stride in pairs (136B: slots stagger
                            // 8B mod 128; rowgroup delta 544B = 32 mod 128)
#define CPW   18            // hbC slot stride in floats (72B; rowgroup delta
                            // 32 mod 128 -> exactly 2 lanes/bank on b32 reads)
#define NTX   32            // 2048/64
#define NTY   16            // 2048/128
#define NBLOCKS (NTX*NTY*NCH)   // 1536
#define NOUT_TOTAL 12460332.0f  // 3 * 2038 * 2038

// SSIM per-pixel term. rcpf: denominators >= 9e-4, rel err ~1e-6 vs 2e-2
// threshold.
__device__ __forceinline__ float ssim_term(float mu1, float mu2,
                                           float b11, float b22, float b12) {
    const float c1v = 1e-4f, c2v = 9e-4f;
    float mu1sq = mu1 * mu1;
    float mu2sq = mu2 * mu2;
    float mu12  = mu1 * mu2;
    float s11 = b11 - mu1sq;
    float s22 = b22 - mu2sq;
    float s12 = b12 - mu12;
    float csn = 2.f * s12 + c2v;
    float csd = s11 + s22 + c2v;
    float ln  = 2.f * mu12 + c1v;
    float ld  = mu1sq + mu2sq + c1v;
    return (csn * ln) * __builtin_amdgcn_rcpf(csd * ld);
}

// R16 = R9's exact per-lane work at WAVE granularity: each wave owns a
// private 16-col strip + private LDS ring -> producer and consumer are the
// same wave -> within-wave in-order DS pipe + compiler lgkmcnt replace ALL
// __syncthreads (zero barriers in the main loop). Isolates the last untested
// structural variable: R9's 17 all-wave barrier drains (each forces
// vmcnt(0)+lgkmcnt(0) convoy while PF's ~900cy HBM latency exceeds stage C's
// ~700cy cover). Work per lane is bit-identical to R9: BLUR = 4 h-cols from
// 14 inputs (pk over (x,y)), C = 1 col x 4 rows sliding 14-slot window, FP
// order per output unchanged. LDS 38.5 KB -> 4 blocks/CU (same as R9).
// Ledger: OH=64 (R10), pk-xy (R11), CROWS=8 (R12), fused row (R13), 2-deep
// PF (R14), column-streaming (R15) all regressed vs R9's 74us.
// fp32 throughout (R5). __launch_bounds__(256,2) ((256,4) -> spill, R3).
__global__ __launch_bounds__(256, 2)
void ssim_main(const float* __restrict__ x, const float* __restrict__ y,
               float* __restrict__ partials) {
    __shared__ f32x2 hbA[4][BUF][APW];   // (mu1,mu2) rings: 14.9 KB
    __shared__ f32x2 hbB[4][BUF][APW];   // (xx,yy)  rings: 14.9 KB
    __shared__ float hbC[4][BUF][CPW];   // xy       rings:  7.9 KB
    __shared__ float wsum[4];            // total 38.5 KB -> 4 blocks/CU

    const int tid  = threadIdx.x;
    const int lane = tid & 63;
    const int wid  = tid >> 6;
    const int gx0  = blockIdx.x * OWID + wid * SW;   // wave's col base
    const int gy0  = blockIdx.y * OH;
    const float* xb = x + (size_t)blockIdx.z * HH * WW;
    const float* yb = y + (size_t)blockIdx.z * HH * WW;

    // Gaussian weights (11 taps, sigma 1.5), normalized — matches jnp f32
    float w[11];
    {
        float s = 0.f;
        #pragma unroll
        for (int i = 0; i < 11; ++i) {
            float d = (float)(i - 5);
            w[i] = expf(-d * d / 4.5f);
            s += w[i];
        }
        float inv = 1.f / s;
        #pragma unroll
        for (int i = 0; i < 11; ++i) w[i] *= inv;
    }

    // BLUR/PF geometry: lane (lr, c0) produces ring row lr of this wave's
    // strip, cols [c0, c0+4) from input cols [c0, c0+14). 16 rows x 4 groups.
    const int lr  = lane >> 2;           // 0..15
    const int c0  = (lane & 3) * 4;      // 0,4,8,12
    const int gxc = gx0 + c0;

    // Prefetch registers: 14 input cols x 2 images, live across stage C.
    f32x4 px[3], py[3];
    f32x2 px3, py3;

    // Issue the global loads for h-rows [base, base+16) (this lane's row).
    auto PF = [&](int base) {
        int gy = gy0 + base + lr; if (gy > HH - 1) gy = HH - 1;
        const float* xr = xb + (size_t)gy * WW;
        const float* yr = yb + (size_t)gy * WW;
        #pragma unroll
        for (int a = 0; a < 3; ++a) {
            int g = gxc + 4 * a;
            if (g + 4 <= WW) {
                px[a] = *(const f32x4*)(xr + g);
                py[a] = *(const f32x4*)(yr + g);
            } else {  // right-edge clamp; feeds only masked outputs
                int g0 = g     < WW ? g     : WW - 1;
                int g1 = g + 1 < WW ? g + 1 : WW - 1;
                int g2 = g + 2 < WW ? g + 2 : WW - 1;
                int g3 = g + 3 < WW ? g + 3 : WW - 1;
                px[a] = (f32x4){xr[g0], xr[g1], xr[g2], xr[g3]};
                py[a] = (f32x4){yr[g0], yr[g1], yr[g2], yr[g3]};
            }
        }
        {
            int g = gxc + 12;
            if (g + 2 <= WW) {
                px3 = *(const f32x2*)(xr + g);
                py3 = *(const f32x2*)(yr + g);
            } else {
                int g0 = g     < WW ? g     : WW - 1;
                int g1 = g + 1 < WW ? g + 1 : WW - 1;
                px3 = (f32x2){xr[g0], xr[g1]};
                py3 = (f32x2){yr[g0], yr[g1]};
            }
        }
    };

    // h-blur the prefetched row into this wave's ring slot (base+lr)%28.
    // tailMask: prologue partial chunk (rows [16,26)) — lanes lr>=10 compute
    // but must not store (their slot aliases live rows 0..3).
    auto BLUR = [&](int base, bool tailMask) {
        int slot = (base + lr) % BUF;
        f32x2 p[14];
        #pragma unroll
        for (int a = 0; a < 3; ++a)
            #pragma unroll
            for (int i = 0; i < 4; ++i)
                p[4 * a + i] = (f32x2){px[a][i], py[a][i]};
        p[12] = (f32x2){px3.x, py3.x};
        p[13] = (f32x2){px3.y, py3.y};
        f32x2 q[14]; float pr[14];
        #pragma unroll
        for (int t = 0; t < 14; ++t) {
            q[t]  = p[t] * p[t];             // v_pk_mul_f32
            pr[t] = p[t].x * p[t].y;
        }
        f32x2 hA[4] = {}, hB[4] = {};
        float hC[4] = {};
        #pragma unroll
        for (int k = 0; k < 11; ++k) {
            f32x2 wk2 = (f32x2){w[k], w[k]};
            #pragma unroll
            for (int j = 0; j < 4; ++j) {
                hA[j] = __builtin_elementwise_fma(wk2, p[j + k], hA[j]);
                hB[j] = __builtin_elementwise_fma(wk2, q[j + k], hB[j]);
                hC[j] = fmaf(w[k], pr[j + k], hC[j]);
            }
        }
        if (!tailMask || lr < 10) {
            // A/B: b128 stores (slot base 136B -> 8B-aligned... c0*8 mult of
            // 32, 136*slot: 8B granular => use 2x b128 only when 16B-aligned;
            // slot*136 is 8-mod-16 for odd slots -> use f32x2 pairs (b64).
            f32x2* rA = &hbA[wid][slot][c0];
            f32x2* rB = &hbB[wid][slot][c0];
            rA[0] = hA[0]; rA[1] = hA[1]; rA[2] = hA[2]; rA[3] = hA[3];
            rB[0] = hB[0]; rB[1] = hB[1]; rB[2] = hB[2]; rB[3] = hB[3];
            float* rC = &hbC[wid][slot][c0];
            *(f32x2*)(rC)     = (f32x2){hC[0], hC[1]};
            *(f32x2*)(rC + 2) = (f32x2){hC[2], hC[3]};
        }
    };

    float partial = 0.f;

    // C geometry: lane (rg, cc) = 1 col x 4 rows, sliding 14-slot window.
    const int cc   = lane & 15;          // 0..15
    const int rg   = lane >> 4;          // 0..3
    const int ocol = gx0 + cc;

    auto CSTAGE = [&](int m) {
        const int r0 = 16 * m + rg * 4;
        int s = r0 % BUF;
        f32x2 aA[4] = {}, aB[4] = {};
        float aC[4] = {};
        #pragma unroll
        for (int j = 0; j < 14; ++j) {
            f32x2 va = hbA[wid][s][cc];
            f32x2 vb = hbB[wid][s][cc];
            float vc = hbC[wid][s][cc];
            #pragma unroll
            for (int i = 0; i < 4; ++i) {
                const int k = j - i;
                if (k >= 0 && k < 11) {
                    f32x2 wk2 = (f32x2){w[k], w[k]};
                    aA[i] = __builtin_elementwise_fma(wk2, va, aA[i]);
                    aB[i] = __builtin_elementwise_fma(wk2, vb, aB[i]);
                    aC[i] = fmaf(w[k], vc, aC[i]);
                }
            }
            s = (s == BUF - 1) ? 0 : s + 1;
        }
        #pragma unroll
        for (int i = 0; i < 4; ++i) {
            int orow = gy0 + r0 + i;
            if (orow < NOUT && ocol < NOUT)
                partial += ssim_term(aA[i].x, aA[i].y, aB[i].x, aB[i].y, aC[i]);
        }
    };

    // Prologue: h-rows [0,26) into this wave's ring. No barriers anywhere:
    // the wave's own DS-pipe ordering + compiler waitcnts are sufficient.
    PF(0);  BLUR(0, false);
    PF(16); BLUR(16, true);

    // Main loop: 8 chunks of 16 output rows. Invariant before C(m): ring
    // holds h-rows [16m, 16m+26). PF(m)'s loads are in flight during C(m)
    // (issued before), consumed by BLUR right after — the wave waits only on
    // ITS OWN vmcnt; other waves on the CU proceed independently.
    for (int m = 0; m < 8; ++m) {
        if (m < 7) PF(16 * m + 26);
        CSTAGE(m);
        if (m < 7) BLUR(16 * m + 26, false);
    }

    // Reduction: wave shuffle -> block -> one plain store per block.
    #pragma unroll
    for (int off = 32; off > 0; off >>= 1)
        partial += __shfl_down(partial, off, 64);
    if ((tid & 63) == 0) wsum[tid >> 6] = partial;
    __syncthreads();
    if (tid == 0) {
        int bid = (blockIdx.z * gridDim.y + blockIdx.y) * gridDim.x + blockIdx.x;
        partials[bid] = wsum[0] + wsum[1] + wsum[2] + wsum[3];
    }
}

__global__ __launch_bounds__(256)
void ssim_finalize(const float* __restrict__ partials, float* __restrict__ out) {
    __shared__ float ws[4];
    float s = 0.f;
    // NBLOCKS = 1536 = 384 float4s
    for (int i = threadIdx.x; i < NBLOCKS / 4; i += 256) {
        float4 v = ((const float4*)partials)[i];
        s += (v.x + v.y) + (v.z + v.w);
    }
    #pragma unroll
    for (int off = 32; off > 0; off >>= 1)
        s += __shfl_down(s, off, 64);
    if ((threadIdx.x & 63) == 0) ws[threadIdx.x >> 6] = s;
    __syncthreads();
    if (threadIdx.x == 0)
        out[0] = 1.f - (ws[0] + ws[1] + ws[2] + ws[3]) / NOUT_TOTAL;
}

extern "C" void kernel_launch(void* const* d_in, const int* in_sizes, int n_in,
                              void* d_out, int out_size, void* d_ws, size_t ws_size,
                              hipStream_t stream) {
    const float* x = (const float*)d_in[0];
    const float* y = (const float*)d_in[1];
    float* out = (float*)d_out;
    float* partials = (float*)d_ws;   // NBLOCKS floats = 6 KB of scratch

    dim3 grid(NTX, NTY, NCH);
    ssim_main<<<grid, dim3(256), 0, stream>>>(x, y, partials);
    ssim_finalize<<<1, 256, 0, stream>>>(partials, out);
}